// Round 8
// baseline (474.819 us; speedup 1.0000x reference)
//
#include <hip/hip_runtime.h>
#include <hip/hip_bf16.h>
#include <math.h>

#define DEV __device__ __forceinline__

constexpr int Bb   = 32;
constexpr int Nn   = 128;
constexpr int Ff   = 10;
constexpr int Dd   = 64;
constexpr int TOPK = 20;
constexpr int EXTRA= 25;
constexpr int BN   = 4096;   // B*N
constexpr int TBN  = 8192;   // 2*BN
constexpr float EPS   = 1e-5f;
constexpr float SLOPE = 0.2f;

// order-preserving float<->uint encoding (monotone: a<b  <=> fenc(a)<fenc(b))
DEV unsigned int fenc(float f){
  unsigned int b = __float_as_uint(f);
  return (b & 0x80000000u) ? ~b : (b | 0x80000000u);
}
DEV float fdec(unsigned int u){
  unsigned int b = (u & 0x80000000u) ? (u & 0x7FFFFFFFu) : ~u;
  return __uint_as_float(b);
}

// ---------------- generic zero ----------------
__global__ void k_zero(float* __restrict__ p, int n){
  int i = blockIdx.x*256 + threadIdx.x;
  if(i < n) p[i] = 0.f;
}

// ---------------- emb row norms ----------------
__global__ void k_emb_norm(const float* __restrict__ emb, float* __restrict__ norms){
  int i = blockIdx.x, d = threadIdx.x;
  float v = emb[i*Dd + d];
  float s = v*v;
  for(int o=32;o>0;o>>=1) s += __shfl_down(s, o, 64);
  if(d==0) norms[i] = fmaxf(sqrtf(s), 1e-12f);
}

// ---------------- emb cosine + top-20 per row ----------------
__global__ void k_emb_topk(const float* __restrict__ emb, const float* __restrict__ norms,
                           float* __restrict__ topv, int* __restrict__ topi){
  __shared__ float se[Dd];
  __shared__ float sc[Nn];
  __shared__ float rv[Nn];
  __shared__ int   ri[Nn];
  int i = blockIdx.x, t = threadIdx.x;
  if(t < Dd) se[t] = emb[i*Dd + t];
  __syncthreads();
  float dot = 0.f;
  for(int d=0; d<Dd; d++) dot += se[d]*emb[t*Dd + d];
  sc[t] = dot/(norms[i]*norms[t]);
  __syncthreads();
  for(int k=0; k<TOPK; k++){
    rv[t] = sc[t]; ri[t] = t; __syncthreads();
    for(int o=Nn/2; o>0; o>>=1){
      if(t < o){
        float v2 = rv[t+o]; int i2 = ri[t+o];
        if(v2 > rv[t] || (v2 == rv[t] && i2 < ri[t])){ rv[t]=v2; ri[t]=i2; }
      }
      __syncthreads();
    }
    if(t==0){
      topv[i*TOPK + k] = rv[0];
      topi[i*TOPK + k] = ri[0];
      sc[ri[0]] = -INFINITY;
    }
    __syncthreads();
  }
}

// ---------------- h = x@W1, si/sj attention logits ----------------
__global__ void k_h1(const float* __restrict__ data, const float* __restrict__ emb,
                     const float* __restrict__ W1, const float* __restrict__ ai1,
                     const float* __restrict__ aj1,
                     float* __restrict__ h, float* __restrict__ si, float* __restrict__ sj){
  int r = blockIdx.x, d = threadIdx.x;
  int node = r & (Nn-1);
  __shared__ float xr[Ff];
  if(d < Ff) xr[d] = data[r*Ff + d];
  __syncthreads();
  float hv = 0.f;
  #pragma unroll
  for(int f=0; f<Ff; f++) hv += xr[f]*W1[f*Dd + d];
  h[r*Dd + d] = hv;
  float e = emb[node*Dd + d];
  float a = hv*ai1[d] + e*ai1[Dd + d];
  float b = hv*aj1[d] + e*aj1[Dd + d];
  for(int o=32;o>0;o>>=1){ a += __shfl_down(a,o,64); b += __shfl_down(b,o,64); }
  if(d==0){ si[r] = a; sj[r] = b; }
}

// ---------------- layer-1 segment softmax + aggregation ----------------
__global__ void k_agg1(const float* __restrict__ h, const float* __restrict__ si,
                       const float* __restrict__ sj, const float* __restrict__ topv,
                       const int* __restrict__ topi, const float* __restrict__ bias1,
                       float* __restrict__ agg){
  int r = blockIdx.x, d = threadIdx.x;
  int b = r >> 7, node = r & (Nn-1);
  __shared__ float sal[TOPK];
  __shared__ int   ssrc[TOPK];
  if(d < TOPK){
    int s = b*Nn + topi[node*TOPK + d];
    float sc = si[r] + sj[s];
    sc = sc >= 0.f ? sc : SLOPE*sc;
    sal[d] = sc * topv[node*TOPK + d];
    ssrc[d] = s;
  }
  __syncthreads();
  float m = -INFINITY;
  #pragma unroll
  for(int k=0;k<TOPK;k++) m = fmaxf(m, sal[k]);
  float al[TOPK]; float ssum = 0.f;
  #pragma unroll
  for(int k=0;k<TOPK;k++){ al[k] = expf(sal[k]-m); ssum += al[k]; }
  float inv = 1.0f/fmaxf(ssum, 1e-12f);
  float acc = 0.f;
  #pragma unroll
  for(int k=0;k<TOPK;k++) acc += al[k]*inv*h[ssrc[k]*Dd + d];
  agg[r*Dd + d] = acc + bias1[d];
}

// ---------------- per-channel stats over BN rows (agg1) ----------------
__global__ void k_colstats(const float* __restrict__ x, float* __restrict__ mu, float* __restrict__ var){
  int c = blockIdx.x, t = threadIdx.x;
  float s = 0.f, s2 = 0.f;
  for(int r=t; r<BN; r+=256){ float v = x[r*Dd + c]; s += v; s2 += v*v; }
  __shared__ float ls[256], ls2[256];
  ls[t]=s; ls2[t]=s2; __syncthreads();
  for(int o=128;o>0;o>>=1){
    if(t<o){ ls[t]+=ls[t+o]; ls2[t]+=ls2[t+o]; }
    __syncthreads();
  }
  if(t==0){ float m = ls[0]/BN; mu[c]=m; var[c]=ls2[0]/BN - m*m; }
}

// ---------------- BN1 + relu -> g[0:BN] ----------------
__global__ void k_bnrelu1(const float* __restrict__ agg, const float* __restrict__ mu,
                          const float* __restrict__ var, const float* __restrict__ gamma,
                          const float* __restrict__ beta, float* __restrict__ g){
  int idx = blockIdx.x*256 + threadIdx.x;
  int c = idx & (Dd-1);
  float v = agg[idx];
  float y = gamma[c]*(v - mu[c])/sqrtf(var[c]+EPS) + beta[c];
  g[idx] = fmaxf(y, 0.f);
}

// ---------------- ef = P^T @ gcn : float4 staging, grid (64 j-tiles, 16 r-chunks) ----------------
__global__ __launch_bounds__(256) void k_ef(const float* __restrict__ P, const float* __restrict__ gcn,
                                            float* __restrict__ ef){
  __shared__ float Pt[16*64];
  __shared__ float Gt[16*64];
  int t = threadIdx.x;
  int jbase = blockIdx.x*64;
  int r0 = blockIdx.y*256;
  int row = t >> 4, col4 = (t & 15)*4;
  int tr = t >> 4, tc = t & 15;
  float acc[4][4] = {};
  for(int step=0; step<16; step++){
    int r = r0 + step*16;
    float4 pv = *(const float4*)&P[(size_t)(r+row)*BN + jbase + col4];
    float4 gv = *(const float4*)&gcn[(r+row)*Dd + col4];
    __syncthreads();
    *(float4*)&Pt[row*64 + col4] = pv;
    *(float4*)&Gt[row*64 + col4] = gv;
    __syncthreads();
    #pragma unroll
    for(int rr=0; rr<16; rr++){
      float4 pa = *(float4*)&Pt[rr*64 + tr*4];
      float4 gb = *(float4*)&Gt[rr*64 + tc*4];
      float pav[4] = {pa.x, pa.y, pa.z, pa.w};
      float gbv[4] = {gb.x, gb.y, gb.z, gb.w};
      #pragma unroll
      for(int a=0;a<4;a++)
        #pragma unroll
        for(int b=0;b<4;b++) acc[a][b] += pav[a]*gbv[b];
    }
  }
  #pragma unroll
  for(int a=0;a<4;a++)
    #pragma unroll
    for(int b=0;b<4;b++)
      atomicAdd(&ef[(jbase + tr*4 + a)*Dd + tc*4 + b], acc[a][b]);
}

// ---------------- row norms of g (8192 rows) ----------------
__global__ void k_rownorm(const float* __restrict__ x, float* __restrict__ nrm){
  int r = blockIdx.x, d = threadIdx.x;
  float v = x[(size_t)r*Dd + d];
  float s = v*v;
  for(int o=32;o>0;o>>=1) s += __shfl_down(s, o, 64);
  if(d==0) nrm[r] = fmaxf(sqrtf(s), 1e-12f);
}

// ---------------- S chunk GEMM: S[r][c] = cos(g[rbase+r], g[c]) ----------------
__global__ __launch_bounds__(256) void k_sgemm(const float* __restrict__ g, const float* __restrict__ gnorm,
                                               int rbase, float* __restrict__ S){
  __shared__ float A[64*128];
  __shared__ float Bs[64*128];
  int t = threadIdx.x;
  int ctile = blockIdx.x*128;
  int rtile = rbase + blockIdx.y*128;
  int q = t >> 4, m0 = t & 15;
  #pragma unroll
  for(int l=0;l<8;l++){
    int m = m0 + 16*l;
    float ia = 1.0f/gnorm[rtile + m];
    float ib = 1.0f/gnorm[ctile + m];
    float4 av = *(const float4*)&g[(size_t)(rtile+m)*Dd + q*4];
    float4 bv = *(const float4*)&g[(size_t)(ctile+m)*Dd + q*4];
    A[(q*4+0)*128 + m] = av.x*ia; A[(q*4+1)*128 + m] = av.y*ia;
    A[(q*4+2)*128 + m] = av.z*ia; A[(q*4+3)*128 + m] = av.w*ia;
    Bs[(q*4+0)*128 + m] = bv.x*ib; Bs[(q*4+1)*128 + m] = bv.y*ib;
    Bs[(q*4+2)*128 + m] = bv.z*ib; Bs[(q*4+3)*128 + m] = bv.w*ib;
  }
  __syncthreads();
  int tr = t >> 4;
  int tc = t & 15;
  float acc[8][8] = {};
  #pragma unroll 4
  for(int k=0;k<64;k++){
    float a[8], b[8];
    #pragma unroll
    for(int i=0;i<8;i++) a[i] = A[k*128 + tr + 16*i];
    #pragma unroll
    for(int j=0;j<8;j++) b[j] = Bs[k*128 + tc + 16*j];
    #pragma unroll
    for(int i=0;i<8;i++)
      #pragma unroll
      for(int j=0;j<8;j++) acc[i][j] += a[i]*b[j];
  }
  int rloc = blockIdx.y*128;
  #pragma unroll
  for(int i=0;i<8;i++){
    int r = rloc + tr + 16*i;
    #pragma unroll
    for(int j=0;j<8;j++)
      S[(size_t)r*TBN + ctile + tc + 16*j] = acc[i][j];
  }
}

// ---------------- exact top-25 per row via 4x8-bit radix select ----------------
// Pass 0 uses wave ballot-aggregated histogram updates (digits are exponent-
// concentrated -> plain atomics serialize 64-way); passes 1-3 use plain
// atomics (mantissa digits are near-uniform among the few candidates).
__global__ __launch_bounds__(256) void k_radix(const float* __restrict__ S, int rbase,
                                               float* __restrict__ topv2, int* __restrict__ topi2){
  __shared__ unsigned hist[256];
  __shared__ unsigned scanb[256];
  __shared__ unsigned bc_prefix, bc_need, bc_cnt;
  int t = threadIdx.x;
  int lane = t & 63;
  int r = blockIdx.x;
  const float* src = S + (size_t)r*TBN;
  int col0 = t*32;
  unsigned enc[32];
  #pragma unroll
  for(int j=0;j<8;j++){
    float4 v = *(const float4*)&src[col0 + j*4];
    enc[j*4+0]=fenc(v.x); enc[j*4+1]=fenc(v.y); enc[j*4+2]=fenc(v.z); enc[j*4+3]=fenc(v.w);
  }
  unsigned prefix = 0, need = EXTRA;
  for(int p=0;p<4;p++){
    int shift = 24 - 8*p;
    hist[t] = 0u;
    __syncthreads();
    if(p == 0){
      // ballot-aggregated: iterate distinct digits per wave (few: exponent-concentrated)
      #pragma unroll
      for(int j=0;j<32;j++){
        unsigned digit = enc[j] >> 24;
        unsigned long long rem = ~0ull;
        while(rem){
          int leader = (int)__builtin_ctzll(rem);
          unsigned d0 = (unsigned)__shfl((int)digit, leader, 64);
          unsigned long long mm = __ballot(digit == d0);
          if(lane == leader) atomicAdd(&hist[d0], (unsigned)__builtin_popcountll(mm));
          rem &= ~mm;
        }
      }
    } else {
      #pragma unroll
      for(int j=0;j<32;j++){
        unsigned e = enc[j];
        if((e >> (shift+8)) == prefix) atomicAdd(&hist[(e>>shift)&255u], 1u);
      }
    }
    __syncthreads();
    // inclusive suffix scan: v = sum_{b>=t} hist[b]
    unsigned v = hist[t];
    for(int o=1;o<256;o<<=1){
      scanb[t] = v; __syncthreads();
      if(t+o < 256) v += scanb[t+o];
      __syncthreads();
    }
    scanb[t] = v; __syncthreads();
    unsigned nxt = (t<255) ? scanb[t+1] : 0u;
    if(v >= need && nxt < need){ bc_prefix = (prefix<<8) | (unsigned)t; bc_need = need - nxt; }
    __syncthreads();
    prefix = bc_prefix; need = bc_need;
    __syncthreads();
  }
  unsigned pivot = prefix;   // full 32-bit code of the 25th-largest (ties resolved by `need`)
  if(t==0) bc_cnt = 0u;
  unsigned tie_local = 0u;
  __syncthreads();
  int gr = rbase + r;
  #pragma unroll
  for(int j=0;j<32;j++){
    unsigned e = enc[j];
    if(e > pivot){
      unsigned s = atomicAdd(&bc_cnt, 1u);
      topv2[gr*EXTRA + s] = fdec(e);
      topi2[gr*EXTRA + s] = col0 + j;
    } else if(e == pivot) tie_local++;
  }
  // forward exclusive scan of per-thread tie counts (global idx order = (t, local))
  unsigned iv = tie_local;
  for(int o=1;o<256;o<<=1){
    scanb[t] = iv; __syncthreads();
    if(t >= o) iv += scanb[t-o];
    __syncthreads();
  }
  unsigned rank = iv - tie_local;
  #pragma unroll
  for(int j=0;j<32;j++){
    unsigned e = enc[j];
    if(e == pivot){
      if(rank < need){
        unsigned s = atomicAdd(&bc_cnt, 1u);
        topv2[gr*EXTRA + s] = fdec(e);
        topi2[gr*EXTRA + s] = col0 + j;
      }
      rank++;
    }
  }
}

// ---------------- h2 = g@W2, attention logits ----------------
__global__ void k_h2(const float* __restrict__ g, const float* __restrict__ W2,
                     const float* __restrict__ ai2w, const float* __restrict__ aj2w,
                     float* __restrict__ h2, float* __restrict__ a2i, float* __restrict__ a2j){
  int r = blockIdx.x, d = threadIdx.x;
  __shared__ float gr[Dd];
  gr[d] = g[(size_t)r*Dd + d];
  __syncthreads();
  float hv = 0.f;
  #pragma unroll
  for(int k=0;k<Dd;k++) hv += gr[k]*W2[k*Dd + d];
  h2[(size_t)r*Dd + d] = hv;
  float a = hv*ai2w[d];
  float b = hv*aj2w[d];
  for(int o=32;o>0;o>>=1){ a += __shfl_down(a,o,64); b += __shfl_down(b,o,64); }
  if(d==0){ a2i[r]=a; a2j[r]=b; }
}

// ---------------- layer-2 edge scores + segment max ----------------
__global__ void k_s2(const float* __restrict__ a2i, const float* __restrict__ a2j,
                     const float* __restrict__ topv2, const int* __restrict__ topi2,
                     float* __restrict__ s2, unsigned int* __restrict__ segmax){
  int e = blockIdx.x*256 + threadIdx.x;
  if(e >= BN*EXTRA) return;
  int r = e/EXTRA;
  int dst = topi2[e];
  float sc = a2i[dst] + a2j[r];
  sc = sc >= 0.f ? sc : SLOPE*sc;
  sc *= topv2[e];
  s2[e] = sc;
  atomicMax(&segmax[dst], fenc(sc));
}

// ---------------- exp + segment sum ----------------
__global__ void k_e2(const float* __restrict__ s2, const int* __restrict__ topi2,
                     const unsigned int* __restrict__ segmax,
                     float* __restrict__ e2, float* __restrict__ ssum){
  int e = blockIdx.x*256 + threadIdx.x;
  if(e >= BN*EXTRA) return;
  int dst = topi2[e];
  float m = fdec(segmax[dst]);
  float v = expf(s2[e] - m);
  e2[e] = v;
  atomicAdd(&ssum[dst], v);
}

// ---------------- weighted scatter into agg2 ----------------
__global__ void k_scat(const float* __restrict__ e2, const float* __restrict__ ssum,
                       const int* __restrict__ topi2, const float* __restrict__ h2,
                       float* __restrict__ agg2){
  int idx = blockIdx.x*256 + threadIdx.x;
  int e = idx >> 6, d = idx & 63;
  int dst = topi2[e];
  int src = e/EXTRA;
  float alpha = e2[e]/fmaxf(ssum[dst], 1e-12f);
  atomicAdd(&agg2[(size_t)dst*Dd + d], alpha*h2[(size_t)src*Dd + d]);
}

// ---------------- head stats over x3 = relu(agg2+bias2)*emb ----------------
__global__ void k_headstats(const float* __restrict__ agg2, const float* __restrict__ bias2,
                            const float* __restrict__ emb, float* __restrict__ mu2, float* __restrict__ var2){
  int c = blockIdx.x, t = threadIdx.x;
  float bc = bias2[c];
  float s = 0.f, s2 = 0.f;
  for(int r=t; r<BN; r+=256){
    float v = fmaxf(agg2[(size_t)r*Dd + c] + bc, 0.f) * emb[(r & (Nn-1))*Dd + c];
    s += v; s2 += v*v;
  }
  __shared__ float ls[256], ls2[256];
  ls[t]=s; ls2[t]=s2; __syncthreads();
  for(int o=128;o>0;o>>=1){
    if(t<o){ ls[t]+=ls[t+o]; ls2[t]+=ls2[t+o]; }
    __syncthreads();
  }
  if(t==0){ float m=ls[0]/BN; mu2[c]=m; var2[c]=ls2[0]/BN - m*m; }
}

// ---------------- final: BN + relu + Linear(D,1) ----------------
__global__ void k_out(const float* __restrict__ agg2, const float* __restrict__ bias2,
                      const float* __restrict__ emb, const float* __restrict__ mu2,
                      const float* __restrict__ var2, const float* __restrict__ gO,
                      const float* __restrict__ bO, const float* __restrict__ Wout,
                      const float* __restrict__ bout, float* __restrict__ out){
  int r = blockIdx.x, d = threadIdx.x;
  float v = fmaxf(agg2[(size_t)r*Dd + d] + bias2[d], 0.f) * emb[(r & (Nn-1))*Dd + d];
  float y = gO[d]*(v - mu2[d])/sqrtf(var2[d]+EPS) + bO[d];
  y = fmaxf(y, 0.f)*Wout[d];
  for(int o=32;o>0;o>>=1) y += __shfl_down(y, o, 64);
  if(d==0) out[r] = y + bout[0];
}

extern "C" void kernel_launch(void* const* d_in, const int* in_sizes, int n_in,
                              void* d_out, int out_size, void* d_ws, size_t ws_size,
                              hipStream_t stream){
  const float* data  = (const float*)d_in[0];
  const float* emb   = (const float*)d_in[1];
  const float* W1    = (const float*)d_in[2];
  const float* ai1   = (const float*)d_in[3];
  const float* aj1   = (const float*)d_in[4];
  const float* bias1 = (const float*)d_in[5];
  const float* bn1g  = (const float*)d_in[6];
  const float* bn1b  = (const float*)d_in[7];
  const float* P     = (const float*)d_in[8];
  const float* W2    = (const float*)d_in[9];
  const float* ai2w  = (const float*)d_in[10];
  const float* aj2w  = (const float*)d_in[11];
  const float* bias2 = (const float*)d_in[12];
  const float* bnOg  = (const float*)d_in[13];
  const float* bnOb  = (const float*)d_in[14];
  const float* Wout  = (const float*)d_in[15];
  const float* bout  = (const float*)d_in[16];
  float* out = (float*)d_out;

  char* w = (char*)d_ws;
  auto alloc = [&](size_t nbytes)->char*{
    char* p = w; w += (nbytes + 255) & ~(size_t)255; return p;
  };
  float* norms1 = (float*)alloc(Nn*4);
  float* topv1  = (float*)alloc(Nn*TOPK*4);
  int*   topi1  = (int*)  alloc(Nn*TOPK*4);
  float* h      = (float*)alloc((size_t)BN*Dd*4);
  float* si     = (float*)alloc(BN*4);
  float* sj     = (float*)alloc(BN*4);
  float* agg1   = (float*)alloc((size_t)BN*Dd*4);
  float* mu1    = (float*)alloc(Dd*4);
  float* var1   = (float*)alloc(Dd*4);
  float* g      = (float*)alloc((size_t)TBN*Dd*4);
  float* gnorm  = (float*)alloc(TBN*4);
  float* topv2  = (float*)alloc((size_t)BN*EXTRA*4);
  int*   topi2  = (int*)  alloc((size_t)BN*EXTRA*4);
  float* h2     = (float*)alloc((size_t)TBN*Dd*4);
  float* a2i    = (float*)alloc(TBN*4);
  float* a2j    = (float*)alloc(TBN*4);
  float* s2     = (float*)alloc((size_t)BN*EXTRA*4);
  float* e2     = (float*)alloc((size_t)BN*EXTRA*4);
  // contiguous zero region: agg2 | ssum | segmax
  float* zblock = (float*)alloc(((size_t)TBN*Dd + TBN + TBN)*4);
  float* agg2   = zblock;
  float* ssum   = zblock + (size_t)TBN*Dd;
  unsigned int* segmax = (unsigned int*)(ssum + TBN);
  float* mu2    = (float*)alloc(Dd*4);
  float* var2   = (float*)alloc(Dd*4);

  // adaptive S-chunk (multiple of 128 rows; prefer one big chunk)
  size_t used = (size_t)(w - (char*)d_ws);
  size_t rem  = ws_size > used ? ws_size - used : 0;
  int chunkRows = 4096;
  while(chunkRows > 128 && (size_t)chunkRows*TBN*4 > rem) chunkRows >>= 1;
  float* Schunk = (float*)alloc((size_t)chunkRows*TBN*4);

  // ---- layer 1 ----
  k_emb_norm<<<Nn, 64, 0, stream>>>(emb, norms1);
  k_emb_topk<<<Nn, Nn, 0, stream>>>(emb, norms1, topv1, topi1);
  k_h1<<<BN, 64, 0, stream>>>(data, emb, W1, ai1, aj1, h, si, sj);
  k_agg1<<<BN, 64, 0, stream>>>(h, si, sj, topv1, topi1, bias1, agg1);
  k_colstats<<<Dd, 256, 0, stream>>>(agg1, mu1, var1);
  k_bnrelu1<<<(BN*Dd)/256, 256, 0, stream>>>(agg1, mu1, var1, bn1g, bn1b, g);

  // ---- ef = P^T gcn ----
  k_zero<<<(BN*Dd)/256, 256, 0, stream>>>(g + (size_t)BN*Dd, BN*Dd);
  k_ef<<<dim3(64, 16), 256, 0, stream>>>(P, g, g + (size_t)BN*Dd);

  // ---- cos2 top-25: chunked GEMM + exact radix select ----
  k_rownorm<<<TBN, 64, 0, stream>>>(g, gnorm);
  for(int rbase=0; rbase<BN; rbase+=chunkRows){
    k_sgemm<<<dim3(TBN/128, chunkRows/128), 256, 0, stream>>>(g, gnorm, rbase, Schunk);
    k_radix<<<chunkRows, 256, 0, stream>>>(Schunk, rbase, topv2, topi2);
  }

  // ---- layer 2 ----
  k_h2<<<TBN, 64, 0, stream>>>(g, W2, ai2w, aj2w, h2, a2i, a2j);
  k_zero<<<((TBN*Dd + 2*TBN) + 255)/256, 256, 0, stream>>>(zblock, TBN*Dd + 2*TBN);
  k_s2<<<(BN*EXTRA + 255)/256, 256, 0, stream>>>(a2i, a2j, topv2, topi2, s2, segmax);
  k_e2<<<(BN*EXTRA + 255)/256, 256, 0, stream>>>(s2, topi2, segmax, e2, ssum);
  k_scat<<<(BN*EXTRA*Dd)/256, 256, 0, stream>>>(e2, ssum, topi2, h2, agg2);

  // ---- head ----
  k_headstats<<<Dd, 256, 0, stream>>>(agg2, bias2, emb, mu2, var2);
  k_out<<<BN, 64, 0, stream>>>(agg2, bias2, emb, mu2, var2, bnOg, bnOb, Wout, bout, out);
}

// Round 9
// 412.629 us; speedup vs baseline: 1.1507x; 1.1507x over previous
//
#include <hip/hip_runtime.h>
#include <hip/hip_bf16.h>
#include <math.h>

#define DEV __device__ __forceinline__

constexpr int Bb   = 32;
constexpr int Nn   = 128;
constexpr int Ff   = 10;
constexpr int Dd   = 64;
constexpr int TOPK = 20;
constexpr int EXTRA= 25;
constexpr int BN   = 4096;   // B*N
constexpr int TBN  = 8192;   // 2*BN
constexpr int CAND_CAP = 1024;
constexpr float EPS   = 1e-5f;
constexpr float SLOPE = 0.2f;

// order-preserving float<->uint encoding (monotone: a<b  <=> fenc(a)<fenc(b))
DEV unsigned int fenc(float f){
  unsigned int b = __float_as_uint(f);
  return (b & 0x80000000u) ? ~b : (b | 0x80000000u);
}
DEV float fdec(unsigned int u){
  unsigned int b = (u & 0x80000000u) ? (u & 0x7FFFFFFFu) : ~u;
  return __uint_as_float(b);
}

// ---------------- generic zero ----------------
__global__ void k_zero(float* __restrict__ p, int n){
  int i = blockIdx.x*256 + threadIdx.x;
  if(i < n) p[i] = 0.f;
}

// ---------------- emb row norms ----------------
__global__ void k_emb_norm(const float* __restrict__ emb, float* __restrict__ norms){
  int i = blockIdx.x, d = threadIdx.x;
  float v = emb[i*Dd + d];
  float s = v*v;
  for(int o=32;o>0;o>>=1) s += __shfl_down(s, o, 64);
  if(d==0) norms[i] = fmaxf(sqrtf(s), 1e-12f);
}

// ---------------- emb cosine + top-20 per row ----------------
__global__ void k_emb_topk(const float* __restrict__ emb, const float* __restrict__ norms,
                           float* __restrict__ topv, int* __restrict__ topi){
  __shared__ float se[Dd];
  __shared__ float sc[Nn];
  __shared__ float rv[Nn];
  __shared__ int   ri[Nn];
  int i = blockIdx.x, t = threadIdx.x;
  if(t < Dd) se[t] = emb[i*Dd + t];
  __syncthreads();
  float dot = 0.f;
  for(int d=0; d<Dd; d++) dot += se[d]*emb[t*Dd + d];
  sc[t] = dot/(norms[i]*norms[t]);
  __syncthreads();
  for(int k=0; k<TOPK; k++){
    rv[t] = sc[t]; ri[t] = t; __syncthreads();
    for(int o=Nn/2; o>0; o>>=1){
      if(t < o){
        float v2 = rv[t+o]; int i2 = ri[t+o];
        if(v2 > rv[t] || (v2 == rv[t] && i2 < ri[t])){ rv[t]=v2; ri[t]=i2; }
      }
      __syncthreads();
    }
    if(t==0){
      topv[i*TOPK + k] = rv[0];
      topi[i*TOPK + k] = ri[0];
      sc[ri[0]] = -INFINITY;
    }
    __syncthreads();
  }
}

// ---------------- h = x@W1, si/sj attention logits ----------------
__global__ void k_h1(const float* __restrict__ data, const float* __restrict__ emb,
                     const float* __restrict__ W1, const float* __restrict__ ai1,
                     const float* __restrict__ aj1,
                     float* __restrict__ h, float* __restrict__ si, float* __restrict__ sj){
  int r = blockIdx.x, d = threadIdx.x;
  int node = r & (Nn-1);
  __shared__ float xr[Ff];
  if(d < Ff) xr[d] = data[r*Ff + d];
  __syncthreads();
  float hv = 0.f;
  #pragma unroll
  for(int f=0; f<Ff; f++) hv += xr[f]*W1[f*Dd + d];
  h[r*Dd + d] = hv;
  float e = emb[node*Dd + d];
  float a = hv*ai1[d] + e*ai1[Dd + d];
  float b = hv*aj1[d] + e*aj1[Dd + d];
  for(int o=32;o>0;o>>=1){ a += __shfl_down(a,o,64); b += __shfl_down(b,o,64); }
  if(d==0){ si[r] = a; sj[r] = b; }
}

// ---------------- layer-1 segment softmax + aggregation ----------------
__global__ void k_agg1(const float* __restrict__ h, const float* __restrict__ si,
                       const float* __restrict__ sj, const float* __restrict__ topv,
                       const int* __restrict__ topi, const float* __restrict__ bias1,
                       float* __restrict__ agg){
  int r = blockIdx.x, d = threadIdx.x;
  int b = r >> 7, node = r & (Nn-1);
  __shared__ float sal[TOPK];
  __shared__ int   ssrc[TOPK];
  if(d < TOPK){
    int s = b*Nn + topi[node*TOPK + d];
    float sc = si[r] + sj[s];
    sc = sc >= 0.f ? sc : SLOPE*sc;
    sal[d] = sc * topv[node*TOPK + d];
    ssrc[d] = s;
  }
  __syncthreads();
  float m = -INFINITY;
  #pragma unroll
  for(int k=0;k<TOPK;k++) m = fmaxf(m, sal[k]);
  float al[TOPK]; float ssum = 0.f;
  #pragma unroll
  for(int k=0;k<TOPK;k++){ al[k] = expf(sal[k]-m); ssum += al[k]; }
  float inv = 1.0f/fmaxf(ssum, 1e-12f);
  float acc = 0.f;
  #pragma unroll
  for(int k=0;k<TOPK;k++) acc += al[k]*inv*h[ssrc[k]*Dd + d];
  agg[r*Dd + d] = acc + bias1[d];
}

// ---------------- per-channel stats over BN rows (agg1) ----------------
__global__ void k_colstats(const float* __restrict__ x, float* __restrict__ mu, float* __restrict__ var){
  int c = blockIdx.x, t = threadIdx.x;
  float s = 0.f, s2 = 0.f;
  for(int r=t; r<BN; r+=256){ float v = x[r*Dd + c]; s += v; s2 += v*v; }
  __shared__ float ls[256], ls2[256];
  ls[t]=s; ls2[t]=s2; __syncthreads();
  for(int o=128;o>0;o>>=1){
    if(t<o){ ls[t]+=ls[t+o]; ls2[t]+=ls2[t+o]; }
    __syncthreads();
  }
  if(t==0){ float m = ls[0]/BN; mu[c]=m; var[c]=ls2[0]/BN - m*m; }
}

// ---------------- BN1 + relu -> g[0:BN] ----------------
__global__ void k_bnrelu1(const float* __restrict__ agg, const float* __restrict__ mu,
                          const float* __restrict__ var, const float* __restrict__ gamma,
                          const float* __restrict__ beta, float* __restrict__ g){
  int idx = blockIdx.x*256 + threadIdx.x;
  int c = idx & (Dd-1);
  float v = agg[idx];
  float y = gamma[c]*(v - mu[c])/sqrtf(var[c]+EPS) + beta[c];
  g[idx] = fmaxf(y, 0.f);
}

// ---------------- ef = P^T @ gcn : float4 staging, grid (64 j-tiles, 16 r-chunks) ----------------
__global__ __launch_bounds__(256) void k_ef(const float* __restrict__ P, const float* __restrict__ gcn,
                                            float* __restrict__ ef){
  __shared__ float Pt[16*64];
  __shared__ float Gt[16*64];
  int t = threadIdx.x;
  int jbase = blockIdx.x*64;
  int r0 = blockIdx.y*256;
  int row = t >> 4, col4 = (t & 15)*4;
  int tr = t >> 4, tc = t & 15;
  float acc[4][4] = {};
  for(int step=0; step<16; step++){
    int r = r0 + step*16;
    float4 pv = *(const float4*)&P[(size_t)(r+row)*BN + jbase + col4];
    float4 gv = *(const float4*)&gcn[(r+row)*Dd + col4];
    __syncthreads();
    *(float4*)&Pt[row*64 + col4] = pv;
    *(float4*)&Gt[row*64 + col4] = gv;
    __syncthreads();
    #pragma unroll
    for(int rr=0; rr<16; rr++){
      float4 pa = *(float4*)&Pt[rr*64 + tr*4];
      float4 gb = *(float4*)&Gt[rr*64 + tc*4];
      float pav[4] = {pa.x, pa.y, pa.z, pa.w};
      float gbv[4] = {gb.x, gb.y, gb.z, gb.w};
      #pragma unroll
      for(int a=0;a<4;a++)
        #pragma unroll
        for(int b=0;b<4;b++) acc[a][b] += pav[a]*gbv[b];
    }
  }
  #pragma unroll
  for(int a=0;a<4;a++)
    #pragma unroll
    for(int b=0;b<4;b++)
      atomicAdd(&ef[(jbase + tr*4 + a)*Dd + tc*4 + b], acc[a][b]);
}

// ---------------- row norms of g (8192 rows) ----------------
__global__ void k_rownorm(const float* __restrict__ x, float* __restrict__ nrm){
  int r = blockIdx.x, d = threadIdx.x;
  float v = x[(size_t)r*Dd + d];
  float s = v*v;
  for(int o=32;o>0;o>>=1) s += __shfl_down(s, o, 64);
  if(d==0) nrm[r] = fmaxf(sqrtf(s), 1e-12f);
}

// ---------------- S chunk GEMM: S[r][c] = cos(g[rbase+r], g[c]) ----------------
__global__ __launch_bounds__(256) void k_sgemm(const float* __restrict__ g, const float* __restrict__ gnorm,
                                               int rbase, float* __restrict__ S){
  __shared__ float A[64*128];
  __shared__ float Bs[64*128];
  int t = threadIdx.x;
  int ctile = blockIdx.x*128;
  int rtile = rbase + blockIdx.y*128;
  int q = t >> 4, m0 = t & 15;
  #pragma unroll
  for(int l=0;l<8;l++){
    int m = m0 + 16*l;
    float ia = 1.0f/gnorm[rtile + m];
    float ib = 1.0f/gnorm[ctile + m];
    float4 av = *(const float4*)&g[(size_t)(rtile+m)*Dd + q*4];
    float4 bv = *(const float4*)&g[(size_t)(ctile+m)*Dd + q*4];
    A[(q*4+0)*128 + m] = av.x*ia; A[(q*4+1)*128 + m] = av.y*ia;
    A[(q*4+2)*128 + m] = av.z*ia; A[(q*4+3)*128 + m] = av.w*ia;
    Bs[(q*4+0)*128 + m] = bv.x*ib; Bs[(q*4+1)*128 + m] = bv.y*ib;
    Bs[(q*4+2)*128 + m] = bv.z*ib; Bs[(q*4+3)*128 + m] = bv.w*ib;
  }
  __syncthreads();
  int tr = t >> 4;
  int tc = t & 15;
  float acc[8][8] = {};
  #pragma unroll 4
  for(int k=0;k<64;k++){
    float a[8], b[8];
    #pragma unroll
    for(int i=0;i<8;i++) a[i] = A[k*128 + tr + 16*i];
    #pragma unroll
    for(int j=0;j<8;j++) b[j] = Bs[k*128 + tc + 16*j];
    #pragma unroll
    for(int i=0;i<8;i++)
      #pragma unroll
      for(int j=0;j<8;j++) acc[i][j] += a[i]*b[j];
  }
  int rloc = blockIdx.y*128;
  #pragma unroll
  for(int i=0;i<8;i++){
    int r = rloc + tr + 16*i;
    #pragma unroll
    for(int j=0;j<8;j++)
      S[(size_t)r*TBN + ctile + tc + 16*j] = acc[i][j];
  }
}

// ---------------- exact top-25 per row: single 12-bit histogram + candidate rank ----------------
// One 256-thread block per row. Pass: 4096-bin histogram (bits[31:20], spreads the
// exponent concentration -> low atomic contention), 2-barrier hierarchical suffix
// scan, then exact (enc desc, col asc) rank selection among the pivot-bin
// candidates (expected tens). Guarded 8/8/4-bit radix fallback keeps exactness
// if the pivot bin overflows CAND_CAP.
__global__ __launch_bounds__(256) void k_radix(const float* __restrict__ S, int rbase,
                                               float* __restrict__ topv2, int* __restrict__ topi2){
  __shared__ unsigned hist[4096];
  __shared__ unsigned wtot[4];
  __shared__ unsigned candE[CAND_CAP];
  __shared__ unsigned short candC[CAND_CAP];
  __shared__ unsigned bc_bin, bc_need, bc_cnt, bc_c;
  int t = threadIdx.x;
  int lane = t & 63, wid = t >> 6;
  int r = blockIdx.x;
  const float* src = S + (size_t)r*TBN;
  int col0 = t*32;
  unsigned enc[32];
  #pragma unroll
  for(int j=0;j<8;j++){
    float4 v = *(const float4*)&src[col0 + j*4];
    enc[j*4+0]=fenc(v.x); enc[j*4+1]=fenc(v.y); enc[j*4+2]=fenc(v.z); enc[j*4+3]=fenc(v.w);
  }
  #pragma unroll
  for(int j=0;j<16;j++) hist[t*16 + j] = 0u;
  __syncthreads();
  #pragma unroll
  for(int j=0;j<32;j++) atomicAdd(&hist[enc[j] >> 20], 1u);
  __syncthreads();
  // local sum of this thread's 16 bins
  unsigned lsum = 0u;
  #pragma unroll
  for(int j=0;j<16;j++) lsum += hist[t*16 + j];
  // wave-level inclusive suffix scan of lsum
  unsigned v = lsum;
  #pragma unroll
  for(int o=1;o<64;o<<=1){
    unsigned u = (unsigned)__shfl_down((int)v, o, 64);
    if(lane + o < 64) v += u;
  }
  if(lane == 0) wtot[wid] = v;
  __syncthreads();
  unsigned cross = 0u;
  #pragma unroll
  for(int w2=0;w2<4;w2++) if(w2 > wid) cross += wtot[w2];
  unsigned Tinc = v + cross;           // sum over threads >= t
  unsigned above = Tinc - lsum;        // sum over threads > t  (= cum above my bin range)
  // walk own 16 bins from high to low to find pivot bin
  unsigned run = above;
  #pragma unroll
  for(int b=15;b>=0;b--){
    unsigned prev = run;
    run += hist[t*16 + b];
    if(run >= EXTRA && prev < EXTRA){ bc_bin = (unsigned)(t*16 + b); bc_need = EXTRA - prev; }
  }
  if(t==0){ bc_cnt = 0u; bc_c = 0u; }
  __syncthreads();
  unsigned pivotBin = bc_bin, needIn = bc_need;
  int gr = rbase + r;
  // emit definite winners (bin > pivotBin); collect pivot-bin candidates
  #pragma unroll
  for(int j=0;j<32;j++){
    unsigned e = enc[j];
    unsigned bin = e >> 20;
    if(bin > pivotBin){
      unsigned s = atomicAdd(&bc_cnt, 1u);
      topv2[gr*EXTRA + s] = fdec(e);
      topi2[gr*EXTRA + s] = col0 + j;
    } else if(bin == pivotBin){
      unsigned ci = atomicAdd(&bc_c, 1u);
      if(ci < CAND_CAP){ candE[ci] = e; candC[ci] = (unsigned short)(col0 + j); }
    }
  }
  __syncthreads();
  unsigned c = bc_c;
  if(c <= CAND_CAP){
    // exact rank among candidates: (enc desc, col asc); take first needIn
    for(unsigned i=t; i<c; i+=256){
      unsigned ei = candE[i]; unsigned coli = candC[i];
      unsigned rank = 0;
      for(unsigned j2=0;j2<c;j2++){
        unsigned ej = candE[j2];
        rank += (ej > ei) || (ej == ei && candC[j2] < coli);
      }
      if(rank < needIn){
        unsigned s = atomicAdd(&bc_cnt, 1u);
        topv2[gr*EXTRA + s] = fdec(ei);
        topi2[gr*EXTRA + s] = (int)coli;
      }
    }
  } else {
    // ---- rare fallback: finish with 8/8/4-bit radix over pivot-bin elements ----
    unsigned* h256  = hist;          // 256-bin histogram region
    unsigned* scanb = hist + 1024;   // 256-entry scan region
    unsigned prefix = pivotBin;      // resolved top 12 bits
    unsigned need = needIn;
    const int shifts[3] = {12, 4, 0};
    const unsigned masks[3] = {255u, 255u, 15u};
    const int nbins[3] = {256, 256, 16};
    for(int p=0;p<3;p++){
      int sh = shifts[p]; unsigned mk = masks[p]; int nb = nbins[p];
      if(t < nb) h256[t] = 0u;
      __syncthreads();
      int topbits = 20 + (p==0?0: (p==1? -8 : -16));  // bits above current digit: 20,12,4... compute prefix shift
      // prefix comparison shift: bits above current digit start at sh + digitwidth
      #pragma unroll
      for(int j=0;j<32;j++){
        unsigned e = enc[j];
        int pshift = (p==0)? 20 : (p==1? 12 : 4);
        if((e >> pshift) == prefix) atomicAdd(&h256[(e>>sh)&mk], 1u);
      }
      __syncthreads();
      unsigned vv = (t < nb) ? h256[t] : 0u;
      for(int o=1;o<nb;o<<=1){
        if(t < nb) scanb[t] = vv;
        __syncthreads();
        if(t < nb && t+o < nb) vv += scanb[t+o];
        __syncthreads();
      }
      if(t < nb) scanb[t] = vv;
      __syncthreads();
      if(t < nb){
        unsigned nxt = (t < nb-1) ? scanb[t+1] : 0u;
        if(vv >= need && nxt < need){ bc_bin = (prefix << ((p==2)?4:8)) | (unsigned)t; bc_need = need - nxt; }
      }
      __syncthreads();
      prefix = bc_bin; need = bc_need;
      __syncthreads();
    }
    unsigned pivotEnc = prefix;
    unsigned needTies = need;
    unsigned tie_local = 0u;
    #pragma unroll
    for(int j=0;j<32;j++){
      unsigned e = enc[j];
      if((e >> 20) == pivotBin){
        if(e > pivotEnc){
          unsigned s = atomicAdd(&bc_cnt, 1u);
          topv2[gr*EXTRA + s] = fdec(e);
          topi2[gr*EXTRA + s] = col0 + j;
        } else if(e == pivotEnc) tie_local++;
      }
    }
    // forward exclusive scan of tie counts
    unsigned iv = tie_local;
    for(int o=1;o<256;o<<=1){
      scanb[t] = iv; __syncthreads();
      if(t >= o) iv += scanb[t-o];
      __syncthreads();
    }
    unsigned rank = iv - tie_local;
    #pragma unroll
    for(int j=0;j<32;j++){
      unsigned e = enc[j];
      if(e == pivotEnc && (e >> 20) == pivotBin){
        if(rank < needTies){
          unsigned s = atomicAdd(&bc_cnt, 1u);
          topv2[gr*EXTRA + s] = fdec(e);
          topi2[gr*EXTRA + s] = col0 + j;
        }
        rank++;
      }
    }
  }
}

// ---------------- h2 = g@W2, attention logits ----------------
__global__ void k_h2(const float* __restrict__ g, const float* __restrict__ W2,
                     const float* __restrict__ ai2w, const float* __restrict__ aj2w,
                     float* __restrict__ h2, float* __restrict__ a2i, float* __restrict__ a2j){
  int r = blockIdx.x, d = threadIdx.x;
  __shared__ float gr[Dd];
  gr[d] = g[(size_t)r*Dd + d];
  __syncthreads();
  float hv = 0.f;
  #pragma unroll
  for(int k=0;k<Dd;k++) hv += gr[k]*W2[k*Dd + d];
  h2[(size_t)r*Dd + d] = hv;
  float a = hv*ai2w[d];
  float b = hv*aj2w[d];
  for(int o=32;o>0;o>>=1){ a += __shfl_down(a,o,64); b += __shfl_down(b,o,64); }
  if(d==0){ a2i[r]=a; a2j[r]=b; }
}

// ---------------- layer-2 edge scores + segment max ----------------
__global__ void k_s2(const float* __restrict__ a2i, const float* __restrict__ a2j,
                     const float* __restrict__ topv2, const int* __restrict__ topi2,
                     float* __restrict__ s2, unsigned int* __restrict__ segmax){
  int e = blockIdx.x*256 + threadIdx.x;
  if(e >= BN*EXTRA) return;
  int r = e/EXTRA;
  int dst = topi2[e];
  float sc = a2i[dst] + a2j[r];
  sc = sc >= 0.f ? sc : SLOPE*sc;
  sc *= topv2[e];
  s2[e] = sc;
  atomicMax(&segmax[dst], fenc(sc));
}

// ---------------- exp + segment sum ----------------
__global__ void k_e2(const float* __restrict__ s2, const int* __restrict__ topi2,
                     const unsigned int* __restrict__ segmax,
                     float* __restrict__ e2, float* __restrict__ ssum){
  int e = blockIdx.x*256 + threadIdx.x;
  if(e >= BN*EXTRA) return;
  int dst = topi2[e];
  float m = fdec(segmax[dst]);
  float v = expf(s2[e] - m);
  e2[e] = v;
  atomicAdd(&ssum[dst], v);
}

// ---------------- weighted scatter into agg2 ----------------
__global__ void k_scat(const float* __restrict__ e2, const float* __restrict__ ssum,
                       const int* __restrict__ topi2, const float* __restrict__ h2,
                       float* __restrict__ agg2){
  int idx = blockIdx.x*256 + threadIdx.x;
  int e = idx >> 6, d = idx & 63;
  int dst = topi2[e];
  int src = e/EXTRA;
  float alpha = e2[e]/fmaxf(ssum[dst], 1e-12f);
  atomicAdd(&agg2[(size_t)dst*Dd + d], alpha*h2[(size_t)src*Dd + d]);
}

// ---------------- head stats over x3 = relu(agg2+bias2)*emb ----------------
__global__ void k_headstats(const float* __restrict__ agg2, const float* __restrict__ bias2,
                            const float* __restrict__ emb, float* __restrict__ mu2, float* __restrict__ var2){
  int c = blockIdx.x, t = threadIdx.x;
  float bc = bias2[c];
  float s = 0.f, s2 = 0.f;
  for(int r=t; r<BN; r+=256){
    float v = fmaxf(agg2[(size_t)r*Dd + c] + bc, 0.f) * emb[(r & (Nn-1))*Dd + c];
    s += v; s2 += v*v;
  }
  __shared__ float ls[256], ls2[256];
  ls[t]=s; ls2[t]=s2; __syncthreads();
  for(int o=128;o>0;o>>=1){
    if(t<o){ ls[t]+=ls[t+o]; ls2[t]+=ls2[t+o]; }
    __syncthreads();
  }
  if(t==0){ float m=ls[0]/BN; mu2[c]=m; var2[c]=ls2[0]/BN - m*m; }
}

// ---------------- final: BN + relu + Linear(D,1) ----------------
__global__ void k_out(const float* __restrict__ agg2, const float* __restrict__ bias2,
                      const float* __restrict__ emb, const float* __restrict__ mu2,
                      const float* __restrict__ var2, const float* __restrict__ gO,
                      const float* __restrict__ bO, const float* __restrict__ Wout,
                      const float* __restrict__ bout, float* __restrict__ out){
  int r = blockIdx.x, d = threadIdx.x;
  float v = fmaxf(agg2[(size_t)r*Dd + d] + bias2[d], 0.f) * emb[(r & (Nn-1))*Dd + d];
  float y = gO[d]*(v - mu2[d])/sqrtf(var2[d]+EPS) + bO[d];
  y = fmaxf(y, 0.f)*Wout[d];
  for(int o=32;o>0;o>>=1) y += __shfl_down(y, o, 64);
  if(d==0) out[r] = y + bout[0];
}

extern "C" void kernel_launch(void* const* d_in, const int* in_sizes, int n_in,
                              void* d_out, int out_size, void* d_ws, size_t ws_size,
                              hipStream_t stream){
  const float* data  = (const float*)d_in[0];
  const float* emb   = (const float*)d_in[1];
  const float* W1    = (const float*)d_in[2];
  const float* ai1   = (const float*)d_in[3];
  const float* aj1   = (const float*)d_in[4];
  const float* bias1 = (const float*)d_in[5];
  const float* bn1g  = (const float*)d_in[6];
  const float* bn1b  = (const float*)d_in[7];
  const float* P     = (const float*)d_in[8];
  const float* W2    = (const float*)d_in[9];
  const float* ai2w  = (const float*)d_in[10];
  const float* aj2w  = (const float*)d_in[11];
  const float* bias2 = (const float*)d_in[12];
  const float* bnOg  = (const float*)d_in[13];
  const float* bnOb  = (const float*)d_in[14];
  const float* Wout  = (const float*)d_in[15];
  const float* bout  = (const float*)d_in[16];
  float* out = (float*)d_out;

  char* w = (char*)d_ws;
  auto alloc = [&](size_t nbytes)->char*{
    char* p = w; w += (nbytes + 255) & ~(size_t)255; return p;
  };
  float* norms1 = (float*)alloc(Nn*4);
  float* topv1  = (float*)alloc(Nn*TOPK*4);
  int*   topi1  = (int*)  alloc(Nn*TOPK*4);
  float* h      = (float*)alloc((size_t)BN*Dd*4);
  float* si     = (float*)alloc(BN*4);
  float* sj     = (float*)alloc(BN*4);
  float* agg1   = (float*)alloc((size_t)BN*Dd*4);
  float* mu1    = (float*)alloc(Dd*4);
  float* var1   = (float*)alloc(Dd*4);
  float* g      = (float*)alloc((size_t)TBN*Dd*4);
  float* gnorm  = (float*)alloc(TBN*4);
  float* topv2  = (float*)alloc((size_t)BN*EXTRA*4);
  int*   topi2  = (int*)  alloc((size_t)BN*EXTRA*4);
  float* h2     = (float*)alloc((size_t)TBN*Dd*4);
  float* a2i    = (float*)alloc(TBN*4);
  float* a2j    = (float*)alloc(TBN*4);
  float* s2     = (float*)alloc((size_t)BN*EXTRA*4);
  float* e2     = (float*)alloc((size_t)BN*EXTRA*4);
  // contiguous zero region: agg2 | ssum | segmax
  float* zblock = (float*)alloc(((size_t)TBN*Dd + TBN + TBN)*4);
  float* agg2   = zblock;
  float* ssum   = zblock + (size_t)TBN*Dd;
  unsigned int* segmax = (unsigned int*)(ssum + TBN);
  float* mu2    = (float*)alloc(Dd*4);
  float* var2   = (float*)alloc(Dd*4);

  // adaptive S-chunk (multiple of 128 rows; prefer one big chunk)
  size_t used = (size_t)(w - (char*)d_ws);
  size_t rem  = ws_size > used ? ws_size - used : 0;
  int chunkRows = 4096;
  while(chunkRows > 128 && (size_t)chunkRows*TBN*4 > rem) chunkRows >>= 1;
  float* Schunk = (float*)alloc((size_t)chunkRows*TBN*4);

  // ---- layer 1 ----
  k_emb_norm<<<Nn, 64, 0, stream>>>(emb, norms1);
  k_emb_topk<<<Nn, Nn, 0, stream>>>(emb, norms1, topv1, topi1);
  k_h1<<<BN, 64, 0, stream>>>(data, emb, W1, ai1, aj1, h, si, sj);
  k_agg1<<<BN, 64, 0, stream>>>(h, si, sj, topv1, topi1, bias1, agg1);
  k_colstats<<<Dd, 256, 0, stream>>>(agg1, mu1, var1);
  k_bnrelu1<<<(BN*Dd)/256, 256, 0, stream>>>(agg1, mu1, var1, bn1g, bn1b, g);

  // ---- ef = P^T gcn ----
  k_zero<<<(BN*Dd)/256, 256, 0, stream>>>(g + (size_t)BN*Dd, BN*Dd);
  k_ef<<<dim3(64, 16), 256, 0, stream>>>(P, g, g + (size_t)BN*Dd);

  // ---- cos2 top-25: chunked GEMM + exact radix select ----
  k_rownorm<<<TBN, 64, 0, stream>>>(g, gnorm);
  for(int rbase=0; rbase<BN; rbase+=chunkRows){
    k_sgemm<<<dim3(TBN/128, chunkRows/128), 256, 0, stream>>>(g, gnorm, rbase, Schunk);
    k_radix<<<chunkRows, 256, 0, stream>>>(Schunk, rbase, topv2, topi2);
  }

  // ---- layer 2 ----
  k_h2<<<TBN, 64, 0, stream>>>(g, W2, ai2w, aj2w, h2, a2i, a2j);
  k_zero<<<((TBN*Dd + 2*TBN) + 255)/256, 256, 0, stream>>>(zblock, TBN*Dd + 2*TBN);
  k_s2<<<(BN*EXTRA + 255)/256, 256, 0, stream>>>(a2i, a2j, topv2, topi2, s2, segmax);
  k_e2<<<(BN*EXTRA + 255)/256, 256, 0, stream>>>(s2, topi2, segmax, e2, ssum);
  k_scat<<<(BN*EXTRA*Dd)/256, 256, 0, stream>>>(e2, ssum, topi2, h2, agg2);

  // ---- head ----
  k_headstats<<<Dd, 256, 0, stream>>>(agg2, bias2, emb, mu2, var2);
  k_out<<<BN, 64, 0, stream>>>(agg2, bias2, emb, mu2, var2, bnOg, bnOb, Wout, bout, out);
}

// Round 10
// 381.395 us; speedup vs baseline: 1.2450x; 1.0819x over previous
//
#include <hip/hip_runtime.h>
#include <hip/hip_bf16.h>
#include <math.h>

#define DEV __device__ __forceinline__

constexpr int Bb   = 32;
constexpr int Nn   = 128;
constexpr int Ff   = 10;
constexpr int Dd   = 64;
constexpr int TOPK = 20;
constexpr int EXTRA= 25;
constexpr int BN   = 4096;   // B*N
constexpr int TBN  = 8192;   // 2*BN
constexpr int RC   = 16;     // r-chunks for split-K ef
constexpr int CAND_CAP = 1024;
constexpr float EPS   = 1e-5f;
constexpr float SLOPE = 0.2f;

// order-preserving float<->uint encoding (monotone: a<b  <=> fenc(a)<fenc(b))
DEV unsigned int fenc(float f){
  unsigned int b = __float_as_uint(f);
  return (b & 0x80000000u) ? ~b : (b | 0x80000000u);
}
DEV float fdec(unsigned int u){
  unsigned int b = (u & 0x80000000u) ? (u & 0x7FFFFFFFu) : ~u;
  return __uint_as_float(b);
}

// ---------------- generic zero ----------------
__global__ void k_zero(float* __restrict__ p, int n){
  int i = blockIdx.x*256 + threadIdx.x;
  if(i < n) p[i] = 0.f;
}

// ---------------- emb row norms ----------------
__global__ void k_emb_norm(const float* __restrict__ emb, float* __restrict__ norms){
  int i = blockIdx.x, d = threadIdx.x;
  float v = emb[i*Dd + d];
  float s = v*v;
  for(int o=32;o>0;o>>=1) s += __shfl_down(s, o, 64);
  if(d==0) norms[i] = fmaxf(sqrtf(s), 1e-12f);
}

// ---------------- emb cosine + top-20 per row ----------------
__global__ void k_emb_topk(const float* __restrict__ emb, const float* __restrict__ norms,
                           float* __restrict__ topv, int* __restrict__ topi){
  __shared__ float se[Dd];
  __shared__ float sc[Nn];
  __shared__ float rv[Nn];
  __shared__ int   ri[Nn];
  int i = blockIdx.x, t = threadIdx.x;
  if(t < Dd) se[t] = emb[i*Dd + t];
  __syncthreads();
  float dot = 0.f;
  for(int d=0; d<Dd; d++) dot += se[d]*emb[t*Dd + d];
  sc[t] = dot/(norms[i]*norms[t]);
  __syncthreads();
  for(int k=0; k<TOPK; k++){
    rv[t] = sc[t]; ri[t] = t; __syncthreads();
    for(int o=Nn/2; o>0; o>>=1){
      if(t < o){
        float v2 = rv[t+o]; int i2 = ri[t+o];
        if(v2 > rv[t] || (v2 == rv[t] && i2 < ri[t])){ rv[t]=v2; ri[t]=i2; }
      }
      __syncthreads();
    }
    if(t==0){
      topv[i*TOPK + k] = rv[0];
      topi[i*TOPK + k] = ri[0];
      sc[ri[0]] = -INFINITY;
    }
    __syncthreads();
  }
}

// ---------------- h = x@W1, si/sj attention logits ----------------
__global__ void k_h1(const float* __restrict__ data, const float* __restrict__ emb,
                     const float* __restrict__ W1, const float* __restrict__ ai1,
                     const float* __restrict__ aj1,
                     float* __restrict__ h, float* __restrict__ si, float* __restrict__ sj){
  int r = blockIdx.x, d = threadIdx.x;
  int node = r & (Nn-1);
  __shared__ float xr[Ff];
  if(d < Ff) xr[d] = data[r*Ff + d];
  __syncthreads();
  float hv = 0.f;
  #pragma unroll
  for(int f=0; f<Ff; f++) hv += xr[f]*W1[f*Dd + d];
  h[r*Dd + d] = hv;
  float e = emb[node*Dd + d];
  float a = hv*ai1[d] + e*ai1[Dd + d];
  float b = hv*aj1[d] + e*aj1[Dd + d];
  for(int o=32;o>0;o>>=1){ a += __shfl_down(a,o,64); b += __shfl_down(b,o,64); }
  if(d==0){ si[r] = a; sj[r] = b; }
}

// ---------------- layer-1 segment softmax + aggregation ----------------
__global__ void k_agg1(const float* __restrict__ h, const float* __restrict__ si,
                       const float* __restrict__ sj, const float* __restrict__ topv,
                       const int* __restrict__ topi, const float* __restrict__ bias1,
                       float* __restrict__ agg){
  int r = blockIdx.x, d = threadIdx.x;
  int b = r >> 7, node = r & (Nn-1);
  __shared__ float sal[TOPK];
  __shared__ int   ssrc[TOPK];
  if(d < TOPK){
    int s = b*Nn + topi[node*TOPK + d];
    float sc = si[r] + sj[s];
    sc = sc >= 0.f ? sc : SLOPE*sc;
    sal[d] = sc * topv[node*TOPK + d];
    ssrc[d] = s;
  }
  __syncthreads();
  float m = -INFINITY;
  #pragma unroll
  for(int k=0;k<TOPK;k++) m = fmaxf(m, sal[k]);
  float al[TOPK]; float ssum = 0.f;
  #pragma unroll
  for(int k=0;k<TOPK;k++){ al[k] = expf(sal[k]-m); ssum += al[k]; }
  float inv = 1.0f/fmaxf(ssum, 1e-12f);
  float acc = 0.f;
  #pragma unroll
  for(int k=0;k<TOPK;k++) acc += al[k]*inv*h[ssrc[k]*Dd + d];
  agg[r*Dd + d] = acc + bias1[d];
}

// ---------------- per-channel stats over BN rows (agg1) ----------------
__global__ void k_colstats(const float* __restrict__ x, float* __restrict__ mu, float* __restrict__ var){
  int c = blockIdx.x, t = threadIdx.x;
  float s = 0.f, s2 = 0.f;
  for(int r=t; r<BN; r+=256){ float v = x[r*Dd + c]; s += v; s2 += v*v; }
  __shared__ float ls[256], ls2[256];
  ls[t]=s; ls2[t]=s2; __syncthreads();
  for(int o=128;o>0;o>>=1){
    if(t<o){ ls[t]+=ls[t+o]; ls2[t]+=ls2[t+o]; }
    __syncthreads();
  }
  if(t==0){ float m = ls[0]/BN; mu[c]=m; var[c]=ls2[0]/BN - m*m; }
}

// ---------------- BN1 + relu -> g[0:BN] ----------------
__global__ void k_bnrelu1(const float* __restrict__ agg, const float* __restrict__ mu,
                          const float* __restrict__ var, const float* __restrict__ gamma,
                          const float* __restrict__ beta, float* __restrict__ g){
  int idx = blockIdx.x*256 + threadIdx.x;
  int c = idx & (Dd-1);
  float v = agg[idx];
  float y = gamma[c]*(v - mu[c])/sqrtf(var[c]+EPS) + beta[c];
  g[idx] = fmaxf(y, 0.f);
}

// ---------------- ef stage 1: partial P^T @ gcn tiles, non-atomic ----------------
__global__ __launch_bounds__(256) void k_ef1(const float* __restrict__ P, const float* __restrict__ gcn,
                                             float* __restrict__ part){
  __shared__ float Pt[16*64];
  __shared__ float Gt[16*64];
  int t = threadIdx.x;
  int jbase = blockIdx.x*64;
  int r0 = blockIdx.y*256;
  int row = t >> 4, col4 = (t & 15)*4;
  int tr = t >> 4, tc = t & 15;
  float acc[4][4] = {};
  for(int step=0; step<16; step++){
    int r = r0 + step*16;
    float4 pv = *(const float4*)&P[(size_t)(r+row)*BN + jbase + col4];
    float4 gv = *(const float4*)&gcn[(r+row)*Dd + col4];
    __syncthreads();
    *(float4*)&Pt[row*64 + col4] = pv;
    *(float4*)&Gt[row*64 + col4] = gv;
    __syncthreads();
    #pragma unroll
    for(int rr=0; rr<16; rr++){
      float4 pa = *(float4*)&Pt[rr*64 + tr*4];
      float4 gb = *(float4*)&Gt[rr*64 + tc*4];
      float pav[4] = {pa.x, pa.y, pa.z, pa.w};
      float gbv[4] = {gb.x, gb.y, gb.z, gb.w};
      #pragma unroll
      for(int a=0;a<4;a++)
        #pragma unroll
        for(int b=0;b<4;b++) acc[a][b] += pav[a]*gbv[b];
    }
  }
  float* dst = part + ((size_t)blockIdx.y*BN + jbase)*Dd;
  #pragma unroll
  for(int a=0;a<4;a++){
    float4 v = make_float4(acc[a][0],acc[a][1],acc[a][2],acc[a][3]);
    *(float4*)&dst[(tr*4+a)*Dd + tc*4] = v;
  }
}

// ---------------- ef stage 2: reduce RC partials ----------------
__global__ void k_ef2(const float* __restrict__ part, float* __restrict__ ef){
  int i = blockIdx.x*256 + threadIdx.x;   // float4 index over BN*Dd/4
  float4 s = make_float4(0.f,0.f,0.f,0.f);
  #pragma unroll
  for(int c=0;c<RC;c++){
    float4 v = *(const float4*)&part[(size_t)c*BN*Dd + (size_t)i*4];
    s.x += v.x; s.y += v.y; s.z += v.z; s.w += v.w;
  }
  *(float4*)&ef[(size_t)i*4] = s;
}

// ---------------- row norms of g (8192 rows) ----------------
__global__ void k_rownorm(const float* __restrict__ x, float* __restrict__ nrm){
  int r = blockIdx.x, d = threadIdx.x;
  float v = x[(size_t)r*Dd + d];
  float s = v*v;
  for(int o=32;o>0;o>>=1) s += __shfl_down(s, o, 64);
  if(d==0) nrm[r] = fmaxf(sqrtf(s), 1e-12f);
}

// ---------------- S chunk GEMM: S[r][c] = cos(g[rbase+r], g[c]) ----------------
__global__ __launch_bounds__(256) void k_sgemm(const float* __restrict__ g, const float* __restrict__ gnorm,
                                               int rbase, float* __restrict__ S){
  __shared__ float A[64*128];
  __shared__ float Bs[64*128];
  int t = threadIdx.x;
  int ctile = blockIdx.x*128;
  int rtile = rbase + blockIdx.y*128;
  int q = t >> 4, m0 = t & 15;
  #pragma unroll
  for(int l=0;l<8;l++){
    int m = m0 + 16*l;
    float ia = 1.0f/gnorm[rtile + m];
    float ib = 1.0f/gnorm[ctile + m];
    float4 av = *(const float4*)&g[(size_t)(rtile+m)*Dd + q*4];
    float4 bv = *(const float4*)&g[(size_t)(ctile+m)*Dd + q*4];
    A[(q*4+0)*128 + m] = av.x*ia; A[(q*4+1)*128 + m] = av.y*ia;
    A[(q*4+2)*128 + m] = av.z*ia; A[(q*4+3)*128 + m] = av.w*ia;
    Bs[(q*4+0)*128 + m] = bv.x*ib; Bs[(q*4+1)*128 + m] = bv.y*ib;
    Bs[(q*4+2)*128 + m] = bv.z*ib; Bs[(q*4+3)*128 + m] = bv.w*ib;
  }
  __syncthreads();
  int tr = t >> 4;
  int tc = t & 15;
  float acc[8][8] = {};
  #pragma unroll 4
  for(int k=0;k<64;k++){
    float a[8], b[8];
    #pragma unroll
    for(int i=0;i<8;i++) a[i] = A[k*128 + tr + 16*i];
    #pragma unroll
    for(int j=0;j<8;j++) b[j] = Bs[k*128 + tc + 16*j];
    #pragma unroll
    for(int i=0;i<8;i++)
      #pragma unroll
      for(int j=0;j<8;j++) acc[i][j] += a[i]*b[j];
  }
  int rloc = blockIdx.y*128;
  #pragma unroll
  for(int i=0;i<8;i++){
    int r = rloc + tr + 16*i;
    #pragma unroll
    for(int j=0;j<8;j++)
      S[(size_t)r*TBN + ctile + tc + 16*j] = acc[i][j];
  }
}

// ---------------- exact top-25 per row: single 12-bit histogram + candidate rank ----------------
__global__ __launch_bounds__(256) void k_radix(const float* __restrict__ S, int rbase,
                                               float* __restrict__ topv2, int* __restrict__ topi2){
  __shared__ unsigned hist[4096];
  __shared__ unsigned wtot[4];
  __shared__ unsigned candE[CAND_CAP];
  __shared__ unsigned short candC[CAND_CAP];
  __shared__ unsigned bc_bin, bc_need, bc_cnt, bc_c;
  int t = threadIdx.x;
  int lane = t & 63, wid = t >> 6;
  int r = blockIdx.x;
  const float* src = S + (size_t)r*TBN;
  int col0 = t*32;
  unsigned enc[32];
  #pragma unroll
  for(int j=0;j<8;j++){
    float4 v = *(const float4*)&src[col0 + j*4];
    enc[j*4+0]=fenc(v.x); enc[j*4+1]=fenc(v.y); enc[j*4+2]=fenc(v.z); enc[j*4+3]=fenc(v.w);
  }
  #pragma unroll
  for(int j=0;j<16;j++) hist[t*16 + j] = 0u;
  __syncthreads();
  #pragma unroll
  for(int j=0;j<32;j++) atomicAdd(&hist[enc[j] >> 20], 1u);
  __syncthreads();
  unsigned lsum = 0u;
  #pragma unroll
  for(int j=0;j<16;j++) lsum += hist[t*16 + j];
  unsigned v = lsum;
  #pragma unroll
  for(int o=1;o<64;o<<=1){
    unsigned u = (unsigned)__shfl_down((int)v, o, 64);
    if(lane + o < 64) v += u;
  }
  if(lane == 0) wtot[wid] = v;
  __syncthreads();
  unsigned cross = 0u;
  #pragma unroll
  for(int w2=0;w2<4;w2++) if(w2 > wid) cross += wtot[w2];
  unsigned Tinc = v + cross;
  unsigned above = Tinc - lsum;
  unsigned run = above;
  #pragma unroll
  for(int b=15;b>=0;b--){
    unsigned prev = run;
    run += hist[t*16 + b];
    if(run >= EXTRA && prev < EXTRA){ bc_bin = (unsigned)(t*16 + b); bc_need = EXTRA - prev; }
  }
  if(t==0){ bc_cnt = 0u; bc_c = 0u; }
  __syncthreads();
  unsigned pivotBin = bc_bin, needIn = bc_need;
  int gr = rbase + r;
  #pragma unroll
  for(int j=0;j<32;j++){
    unsigned e = enc[j];
    unsigned bin = e >> 20;
    if(bin > pivotBin){
      unsigned s = atomicAdd(&bc_cnt, 1u);
      topv2[gr*EXTRA + s] = fdec(e);
      topi2[gr*EXTRA + s] = col0 + j;
    } else if(bin == pivotBin){
      unsigned ci = atomicAdd(&bc_c, 1u);
      if(ci < CAND_CAP){ candE[ci] = e; candC[ci] = (unsigned short)(col0 + j); }
    }
  }
  __syncthreads();
  unsigned c = bc_c;
  if(c <= CAND_CAP){
    for(unsigned i=t; i<c; i+=256){
      unsigned ei = candE[i]; unsigned coli = candC[i];
      unsigned rank = 0;
      for(unsigned j2=0;j2<c;j2++){
        unsigned ej = candE[j2];
        rank += (ej > ei) || (ej == ei && candC[j2] < coli);
      }
      if(rank < needIn){
        unsigned s = atomicAdd(&bc_cnt, 1u);
        topv2[gr*EXTRA + s] = fdec(ei);
        topi2[gr*EXTRA + s] = (int)coli;
      }
    }
  } else {
    // rare fallback: 8/8/4-bit radix over pivot-bin elements
    unsigned* h256  = hist;
    unsigned* scanb = hist + 1024;
    unsigned prefix = pivotBin;
    unsigned need = needIn;
    const int shifts[3] = {12, 4, 0};
    const unsigned masks[3] = {255u, 255u, 15u};
    const int nbins[3] = {256, 256, 16};
    for(int p=0;p<3;p++){
      int sh = shifts[p]; unsigned mk = masks[p]; int nb = nbins[p];
      if(t < nb) h256[t] = 0u;
      __syncthreads();
      #pragma unroll
      for(int j=0;j<32;j++){
        unsigned e = enc[j];
        int pshift = (p==0)? 20 : (p==1? 12 : 4);
        if((e >> pshift) == prefix) atomicAdd(&h256[(e>>sh)&mk], 1u);
      }
      __syncthreads();
      unsigned vv = (t < nb) ? h256[t] : 0u;
      for(int o=1;o<nb;o<<=1){
        if(t < nb) scanb[t] = vv;
        __syncthreads();
        if(t < nb && t+o < nb) vv += scanb[t+o];
        __syncthreads();
      }
      if(t < nb) scanb[t] = vv;
      __syncthreads();
      if(t < nb){
        unsigned nxt = (t < nb-1) ? scanb[t+1] : 0u;
        if(vv >= need && nxt < need){ bc_bin = (prefix << ((p==2)?4:8)) | (unsigned)t; bc_need = need - nxt; }
      }
      __syncthreads();
      prefix = bc_bin; need = bc_need;
      __syncthreads();
    }
    unsigned pivotEnc = prefix;
    unsigned needTies = need;
    unsigned tie_local = 0u;
    #pragma unroll
    for(int j=0;j<32;j++){
      unsigned e = enc[j];
      if((e >> 20) == pivotBin){
        if(e > pivotEnc){
          unsigned s = atomicAdd(&bc_cnt, 1u);
          topv2[gr*EXTRA + s] = fdec(e);
          topi2[gr*EXTRA + s] = col0 + j;
        } else if(e == pivotEnc) tie_local++;
      }
    }
    unsigned iv = tie_local;
    for(int o=1;o<256;o<<=1){
      scanb[t] = iv; __syncthreads();
      if(t >= o) iv += scanb[t-o];
      __syncthreads();
    }
    unsigned rank = iv - tie_local;
    #pragma unroll
    for(int j=0;j<32;j++){
      unsigned e = enc[j];
      if(e == pivotEnc && (e >> 20) == pivotBin){
        if(rank < needTies){
          unsigned s = atomicAdd(&bc_cnt, 1u);
          topv2[gr*EXTRA + s] = fdec(e);
          topi2[gr*EXTRA + s] = col0 + j;
        }
        rank++;
      }
    }
  }
}

// ---------------- h2 = g@W2, attention logits ----------------
__global__ void k_h2(const float* __restrict__ g, const float* __restrict__ W2,
                     const float* __restrict__ ai2w, const float* __restrict__ aj2w,
                     float* __restrict__ h2, float* __restrict__ a2i, float* __restrict__ a2j){
  int r = blockIdx.x, d = threadIdx.x;
  __shared__ float gr[Dd];
  gr[d] = g[(size_t)r*Dd + d];
  __syncthreads();
  float hv = 0.f;
  #pragma unroll
  for(int k=0;k<Dd;k++) hv += gr[k]*W2[k*Dd + d];
  h2[(size_t)r*Dd + d] = hv;
  float a = hv*ai2w[d];
  float b = hv*aj2w[d];
  for(int o=32;o>0;o>>=1){ a += __shfl_down(a,o,64); b += __shfl_down(b,o,64); }
  if(d==0){ a2i[r]=a; a2j[r]=b; }
}

// ---------------- layer-2 edge scores + segment max ----------------
__global__ void k_s2(const float* __restrict__ a2i, const float* __restrict__ a2j,
                     const float* __restrict__ topv2, const int* __restrict__ topi2,
                     float* __restrict__ s2, unsigned int* __restrict__ segmax){
  int e = blockIdx.x*256 + threadIdx.x;
  if(e >= BN*EXTRA) return;
  int r = e/EXTRA;
  int dst = topi2[e];
  float sc = a2i[dst] + a2j[r];
  sc = sc >= 0.f ? sc : SLOPE*sc;
  sc *= topv2[e];
  s2[e] = sc;
  atomicMax(&segmax[dst], fenc(sc));
}

// ---------------- exp + segment sum ----------------
__global__ void k_e2(const float* __restrict__ s2, const int* __restrict__ topi2,
                     const unsigned int* __restrict__ segmax,
                     float* __restrict__ e2, float* __restrict__ ssum){
  int e = blockIdx.x*256 + threadIdx.x;
  if(e >= BN*EXTRA) return;
  int dst = topi2[e];
  float m = fdec(segmax[dst]);
  float v = expf(s2[e] - m);
  e2[e] = v;
  atomicAdd(&ssum[dst], v);
}

// ---------------- weighted scatter into agg2 ----------------
__global__ void k_scat(const float* __restrict__ e2, const float* __restrict__ ssum,
                       const int* __restrict__ topi2, const float* __restrict__ h2,
                       float* __restrict__ agg2){
  int idx = blockIdx.x*256 + threadIdx.x;
  int e = idx >> 6, d = idx & 63;
  int dst = topi2[e];
  int src = e/EXTRA;
  float alpha = e2[e]/fmaxf(ssum[dst], 1e-12f);
  atomicAdd(&agg2[(size_t)dst*Dd + d], alpha*h2[(size_t)src*Dd + d]);
}

// ---------------- head stats over x3 = relu(agg2+bias2)*emb ----------------
__global__ void k_headstats(const float* __restrict__ agg2, const float* __restrict__ bias2,
                            const float* __restrict__ emb, float* __restrict__ mu2, float* __restrict__ var2){
  int c = blockIdx.x, t = threadIdx.x;
  float bc = bias2[c];
  float s = 0.f, s2 = 0.f;
  for(int r=t; r<BN; r+=256){
    float v = fmaxf(agg2[(size_t)r*Dd + c] + bc, 0.f) * emb[(r & (Nn-1))*Dd + c];
    s += v; s2 += v*v;
  }
  __shared__ float ls[256], ls2[256];
  ls[t]=s; ls2[t]=s2; __syncthreads();
  for(int o=128;o>0;o>>=1){
    if(t<o){ ls[t]+=ls[t+o]; ls2[t]+=ls2[t+o]; }
    __syncthreads();
  }
  if(t==0){ float m=ls[0]/BN; mu2[c]=m; var2[c]=ls2[0]/BN - m*m; }
}

// ---------------- final: BN + relu + Linear(D,1) ----------------
__global__ void k_out(const float* __restrict__ agg2, const float* __restrict__ bias2,
                      const float* __restrict__ emb, const float* __restrict__ mu2,
                      const float* __restrict__ var2, const float* __restrict__ gO,
                      const float* __restrict__ bO, const float* __restrict__ Wout,
                      const float* __restrict__ bout, float* __restrict__ out){
  int r = blockIdx.x, d = threadIdx.x;
  float v = fmaxf(agg2[(size_t)r*Dd + d] + bias2[d], 0.f) * emb[(r & (Nn-1))*Dd + d];
  float y = gO[d]*(v - mu2[d])/sqrtf(var2[d]+EPS) + bO[d];
  y = fmaxf(y, 0.f)*Wout[d];
  for(int o=32;o>0;o>>=1) y += __shfl_down(y, o, 64);
  if(d==0) out[r] = y + bout[0];
}

extern "C" void kernel_launch(void* const* d_in, const int* in_sizes, int n_in,
                              void* d_out, int out_size, void* d_ws, size_t ws_size,
                              hipStream_t stream){
  const float* data  = (const float*)d_in[0];
  const float* emb   = (const float*)d_in[1];
  const float* W1    = (const float*)d_in[2];
  const float* ai1   = (const float*)d_in[3];
  const float* aj1   = (const float*)d_in[4];
  const float* bias1 = (const float*)d_in[5];
  const float* bn1g  = (const float*)d_in[6];
  const float* bn1b  = (const float*)d_in[7];
  const float* P     = (const float*)d_in[8];
  const float* W2    = (const float*)d_in[9];
  const float* ai2w  = (const float*)d_in[10];
  const float* aj2w  = (const float*)d_in[11];
  const float* bias2 = (const float*)d_in[12];
  const float* bnOg  = (const float*)d_in[13];
  const float* bnOb  = (const float*)d_in[14];
  const float* Wout  = (const float*)d_in[15];
  const float* bout  = (const float*)d_in[16];
  float* out = (float*)d_out;

  char* w = (char*)d_ws;
  auto alloc = [&](size_t nbytes)->char*{
    char* p = w; w += (nbytes + 255) & ~(size_t)255; return p;
  };
  float* norms1 = (float*)alloc(Nn*4);
  float* topv1  = (float*)alloc(Nn*TOPK*4);
  int*   topi1  = (int*)  alloc(Nn*TOPK*4);
  float* h      = (float*)alloc((size_t)BN*Dd*4);
  float* si     = (float*)alloc(BN*4);
  float* sj     = (float*)alloc(BN*4);
  float* agg1   = (float*)alloc((size_t)BN*Dd*4);
  float* mu1    = (float*)alloc(Dd*4);
  float* var1   = (float*)alloc(Dd*4);
  float* g      = (float*)alloc((size_t)TBN*Dd*4);
  float* gnorm  = (float*)alloc(TBN*4);
  float* topv2  = (float*)alloc((size_t)BN*EXTRA*4);
  int*   topi2  = (int*)  alloc((size_t)BN*EXTRA*4);
  float* h2     = (float*)alloc((size_t)TBN*Dd*4);
  float* a2i    = (float*)alloc(TBN*4);
  float* a2j    = (float*)alloc(TBN*4);
  float* s2     = (float*)alloc((size_t)BN*EXTRA*4);
  float* e2     = (float*)alloc((size_t)BN*EXTRA*4);
  // contiguous zero region: agg2 | ssum | segmax
  float* zblock = (float*)alloc(((size_t)TBN*Dd + TBN + TBN)*4);
  float* agg2   = zblock;
  float* ssum   = zblock + (size_t)TBN*Dd;
  unsigned int* segmax = (unsigned int*)(ssum + TBN);
  float* mu2    = (float*)alloc(Dd*4);
  float* var2   = (float*)alloc(Dd*4);
  float* efpart = (float*)alloc((size_t)RC*BN*Dd*4);   // 16 MB split-K partials

  // adaptive S-chunk (multiple of 128 rows; prefer one big chunk)
  size_t used = (size_t)(w - (char*)d_ws);
  size_t rem  = ws_size > used ? ws_size - used : 0;
  int chunkRows = 4096;
  while(chunkRows > 128 && (size_t)chunkRows*TBN*4 > rem) chunkRows >>= 1;
  float* Schunk = (float*)alloc((size_t)chunkRows*TBN*4);

  // ---- layer 1 ----
  k_emb_norm<<<Nn, 64, 0, stream>>>(emb, norms1);
  k_emb_topk<<<Nn, Nn, 0, stream>>>(emb, norms1, topv1, topi1);
  k_h1<<<BN, 64, 0, stream>>>(data, emb, W1, ai1, aj1, h, si, sj);
  k_agg1<<<BN, 64, 0, stream>>>(h, si, sj, topv1, topi1, bias1, agg1);
  k_colstats<<<Dd, 256, 0, stream>>>(agg1, mu1, var1);
  k_bnrelu1<<<(BN*Dd)/256, 256, 0, stream>>>(agg1, mu1, var1, bn1g, bn1b, g);

  // ---- ef = P^T gcn : split-K, no atomics ----
  k_ef1<<<dim3(64, RC), 256, 0, stream>>>(P, g, efpart);
  k_ef2<<<(BN*Dd/4)/256, 256, 0, stream>>>(efpart, g + (size_t)BN*Dd);

  // ---- cos2 top-25: chunked GEMM + exact radix select ----
  k_rownorm<<<TBN, 64, 0, stream>>>(g, gnorm);
  for(int rbase=0; rbase<BN; rbase+=chunkRows){
    k_sgemm<<<dim3(TBN/128, chunkRows/128), 256, 0, stream>>>(g, gnorm, rbase, Schunk);
    k_radix<<<chunkRows, 256, 0, stream>>>(Schunk, rbase, topv2, topi2);
  }

  // ---- layer 2 ----
  k_h2<<<TBN, 64, 0, stream>>>(g, W2, ai2w, aj2w, h2, a2i, a2j);
  k_zero<<<((TBN*Dd + 2*TBN) + 255)/256, 256, 0, stream>>>(zblock, TBN*Dd + 2*TBN);
  k_s2<<<(BN*EXTRA + 255)/256, 256, 0, stream>>>(a2i, a2j, topv2, topi2, s2, segmax);
  k_e2<<<(BN*EXTRA + 255)/256, 256, 0, stream>>>(s2, topi2, segmax, e2, ssum);
  k_scat<<<(BN*EXTRA*Dd)/256, 256, 0, stream>>>(e2, ssum, topi2, h2, agg2);

  // ---- head ----
  k_headstats<<<Dd, 256, 0, stream>>>(agg2, bias2, emb, mu2, var2);
  k_out<<<BN, 64, 0, stream>>>(agg2, bias2, emb, mu2, var2, bnOg, bnOb, Wout, bout, out);
}